// Round 7
// baseline (1321.834 us; speedup 1.0000x reference)
//
#include <hip/hip_runtime.h>
#include <cstdint>

#define NB 16      // clouds
#define NP 4096    // points per cloud
#define MC 1024    // FPS centers per cloud
#define KNN 64     // neighbors
#define CIN 64     // input feature dim
#define HID 64
#define OUTD 128

typedef __attribute__((ext_vector_type(8))) short bf16x8;
typedef __attribute__((ext_vector_type(4))) float f32x4;
typedef unsigned long long ull;
typedef unsigned short ushort_t;

#define F32_INF __int_as_float(0x7f800000)

// Bit-exact (vs numpy f32) squared distance: no FMA contraction, numpy sum order.
__device__ __forceinline__ float dist2e(float ax, float ay, float az,
                                        float bx, float by, float bz) {
  float dx = __fsub_rn(ax, bx);
  float dy = __fsub_rn(ay, by);
  float dz = __fsub_rn(az, bz);
  return __fadd_rn(__fadd_rn(__fmul_rn(dx, dx), __fmul_rn(dy, dy)), __fmul_rn(dz, dz));
}

// f32 -> bf16 with round-to-nearest-even.
__device__ __forceinline__ ushort_t f2bf(float f) {
  unsigned u = __float_as_uint(f);
  unsigned r = (u + 0x7FFFu + ((u >> 16) & 1u)) >> 16;
  return (ushort_t)r;
}

// ---- DPP helpers: 64-bit key max-reduce on the VALU pipe ----
template <int CTRL>
__device__ __forceinline__ ull kshift(ull k) {
  int lo = (int)(unsigned)(k & 0xffffffffULL);
  int hi = (int)(unsigned)(k >> 32);
  lo = __builtin_amdgcn_update_dpp(lo, lo, CTRL, 0xf, 0xf, false);
  hi = __builtin_amdgcn_update_dpp(hi, hi, CTRL, 0xf, 0xf, false);
  return ((ull)(unsigned)hi << 32) | (ull)(unsigned)lo;
}
template <int CTRL>
__device__ __forceinline__ ull kred(ull k) {
  ull o = kshift<CTRL>(k);
  return (o > k) ? o : k;
}

// ---------- Prep helper: W -> MFMA B-fragment layout ----------
__device__ __forceinline__ void wfrag_entry(const float* __restrict__ W,
                                            ushort_t* __restrict__ out,
                                            int e, int KS, int K, int N) {
  int lane = e & 63, t2 = e >> 6;
  int ks = t2 % KS, nt = t2 / KS;
  int n = nt * 16 + (lane & 15);
  int kb = ks * 32 + ((lane >> 4) & 3) * 8;
#pragma unroll
  for (int j = 0; j < 8; ++j) {
    int k = kb + j;
    float v = (k < K) ? W[(size_t)k * N + n] : 0.f;
    out[(size_t)e * 8 + j] = f2bf(v);
  }
}

// ============ Kernel 1 (fused): FPS (blocks 0..15, round-3 proven core) + prep ============
// key = (f32bits(d) << 32) | ~idx : u64 max == (max d, tie -> lowest idx).
// Round-3 structure exactly: fused min-update + (bd,bi) track -> u64 DPP wave reduce ->
// lane63 kbuf write -> barrier -> uniform kbuf read + 3 selects -> pts[w] read.
// (Rounds 4-6 established every restructuring of this loses: LDS spin-rings storm the
// DS pipe; ballot/readlane inserts VALU<->SALU wait-states; inline coord tracking
// bloats the dist loop. Do not touch without counter evidence.)
__global__ __launch_bounds__(256) void fps_prep_kernel(
    const float* __restrict__ point, const float* __restrict__ xyz,
    const float* __restrict__ W1, const float* __restrict__ W2, const float* __restrict__ W3,
    float* __restrict__ ctr, float* __restrict__ cent_out, float* __restrict__ batch_out,
    ushort_t* __restrict__ xyzbf, ushort_t* __restrict__ w1f,
    ushort_t* __restrict__ w2f, ushort_t* __restrict__ w3f) {
  const int blk = blockIdx.x;
  const int t = threadIdx.x;
  if (blk >= NB) {  // ---- prep path (independent; runs on idle CUs under fps) ----
    const int pb = blk - NB;
    if (pb < 4096) {
      size_t i = ((size_t)pb * 256 + t) * 4;
      float4 v = *(const float4*)(xyz + i);
      unsigned lo = (unsigned)f2bf(v.x) | ((unsigned)f2bf(v.y) << 16);
      unsigned hi = (unsigned)f2bf(v.z) | ((unsigned)f2bf(v.w) << 16);
      uint2 o; o.x = lo; o.y = hi;
      *(uint2*)(xyzbf + i) = o;
    } else {
      for (int e = t; e < 4 * 3 * 64; e += 256) wfrag_entry(W1, w1f, e, 3, CIN + 3, HID);
      for (int e = t; e < 4 * 2 * 64; e += 256) wfrag_entry(W2, w2f, e, 2, HID, HID);
      for (int e = t; e < 8 * 2 * 64; e += 256) wfrag_entry(W3, w3f, e, 2, HID, OUTD);
    }
    return;
  }
  // ---- FPS path (verbatim round-3 core) ----
  const int b = blk;
  const int lane = t & 63, wid = t >> 6;
  __shared__ float4 pts[NP];       // 64 KB
  __shared__ ull kbuf[2][4];
  __shared__ int whist[MC];        // 4 KB
  const float* p = point + (size_t)b * NP * 3;
  for (int i = t; i < NP; i += 256) {
    float4 v; v.x = p[3 * i]; v.y = p[3 * i + 1]; v.z = p[3 * i + 2]; v.w = 0.f;
    pts[i] = v;
  }
  if (t == 0) whist[0] = 0;  // sample 0 is index 0
  __syncthreads();
  float qx[16], qy[16], qz[16], d[16];
#pragma unroll
  for (int r = 0; r < 16; ++r) {
    float4 v = pts[t * 16 + r];
    qx[r] = v.x; qy[r] = v.y; qz[r] = v.z;
    d[r] = F32_INF;                // min(inf, d0) == d0 exactly
  }
  int w = 0;
  for (int it = 1; it < MC; ++it) {
    float4 wp = pts[w];
    float bd = -1.0f; int br = 0;
#pragma unroll
    for (int r = 0; r < 16; ++r) {       // fused min-update + local argmax (first-max wins)
      float nd = dist2e(qx[r], qy[r], qz[r], wp.x, wp.y, wp.z);
      float dv = fminf(d[r], nd);
      d[r] = dv;
      if (dv > bd) { bd = dv; br = r; }
    }
    unsigned gi = (unsigned)(t * 16 + br);
    ull key = ((ull)__float_as_uint(bd) << 32) | (ull)(unsigned)~gi;
    key = kred<0x111>(key);  // row_shr:1
    key = kred<0x112>(key);  // row_shr:2
    key = kred<0x114>(key);  // row_shr:4
    key = kred<0x118>(key);  // row_shr:8   -> lane 15/31/47/63 = row max
    key = kred<0x142>(key);  // row_bcast:15
    key = kred<0x143>(key);  // row_bcast:31 -> lane 63 = wave max
    const int par = it & 1;                // parity: slot reused only after 2 barriers
    if (lane == 63) kbuf[par][wid] = key;
    __syncthreads();
    ull k0 = kbuf[par][0], k1 = kbuf[par][1], k2 = kbuf[par][2], k3 = kbuf[par][3];
    ull ka = (k0 > k1) ? k0 : k1;          // uniform LDS broadcast reads; every lane
    ull kb = (k2 > k3) ? k2 : k3;          // computes w -> no readlane on the path
    ull km = (ka > kb) ? ka : kb;
    w = (int)~(unsigned)(km & 0xffffffffULL);
    if (t == 0) whist[it] = w;             // ds_write: cheap lgkm drain at the barrier
  }
  __syncthreads();
  for (int s = t; s < MC; s += 256) {      // one-shot output writeback
    int wi = whist[s];
    float4 wp = pts[wi];
    size_t o = (size_t)b * MC + s;
    ctr[3*o] = wp.x; ctr[3*o+1] = wp.y; ctr[3*o+2] = wp.z;
    cent_out[3*o] = wp.x; cent_out[3*o+1] = wp.y; cent_out[3*o+2] = wp.z;
    batch_out[o] = (float)b;  // batch = arange // NP == cloud index
  }
}

// ========= Kernel 2 (fused): neighbor selection + MFMA MLP, 4 centers/block =========
// Phase 1 (per wave): round-3 proven radius + K-nearest for this wave's center;
// winners captured in registers (round r's broadcast winner -> lane r), so nidx/ncnt
// never touch global memory. Scratch ld/li overlays the hbuf region (barrier between).
#define HSTRIDE 72   // bf16 elems per hbuf row: 144 B = 16B-aligned, 2-way-conflict-free b128
__global__ __launch_bounds__(256) void neigh_mlp_kernel(
    const ushort_t* __restrict__ xyzbf, const float* __restrict__ point,
    const float* __restrict__ ctr,
    const ushort_t* __restrict__ w1f, const ushort_t* __restrict__ w2f,
    const ushort_t* __restrict__ w3f,
    const float* __restrict__ b1, const float* __restrict__ b2,
    const float* __restrict__ b3,
    float* __restrict__ out) {
  const int wv = threadIdx.x >> 6, lane = threadIdx.x & 63;
  const int quad = lane >> 4, col16 = lane & 15;
  const int c = blockIdx.x * 4 + wv;
  const int bcl = c >> 10;
  const size_t bbase = (size_t)bcl * NP;
  __shared__ __align__(16) char smem[4 * 64 * HSTRIDE * 2];  // 36864 B
  // phase-1 overlay: per-wave {ld[512] f32, li[512] i32} = 4 KB each
  float* ld = (float*)(smem + wv * 4096);
  int*   li = (int*)(smem + wv * 4096 + 2048);
  // phase-2: wave-private hbuf slices
  ushort_t* hb = (ushort_t*)smem + wv * 64 * HSTRIDE;

  const float cx = ctr[3*c], cy = ctr[3*c+1], cz = ctr[3*c+2];
  const float* p = point + bbase * 3;

  // ---- Phase 1: radius + K-nearest (proven shfl comparator) ----
  const float R2 = (float)(0.2 * 0.2);
  int cnt = 0;
  for (int s = 0; s < NP / 64; ++s) {   // compact in-ball candidates into LDS
    int j = s * 64 + lane;
    float d2 = dist2e(cx, cy, cz, p[3*j], p[3*j+1], p[3*j+2]);
    bool v = d2 < R2;
    ull m = __ballot(v);
    if (v) {
      int pos = cnt + __popcll(m & ((1ull << lane) - 1ull));
      if (pos < 512) { ld[pos] = d2; li[pos] = j; }
    }
    cnt += __popcll(m);
  }
  if (cnt > 512) cnt = 512;
  const int nv = (cnt < KNN) ? cnt : KNN;
  int jg;
  if (cnt <= KNN) {
    jg = (lane < cnt) ? li[lane] : 0;   // set-equivalent under masked max-aggregation
  } else {
    float od[8]; int oi[8];
#pragma unroll
    for (int r = 0; r < 8; ++r) {
      int s2 = lane + r * 64;
      if (s2 < cnt) { od[r] = ld[s2]; oi[r] = li[s2]; }
      else { od[r] = F32_INF; oi[r] = 0x7fffffff; }
    }
    jg = 0;
    for (int round = 0; round < KNN; ++round) {  // 64x wave argmin (d2 asc, idx asc)
      float bd = F32_INF; int bi = 0x7fffffff;
#pragma unroll
      for (int r = 0; r < 8; ++r)
        if (od[r] < bd || (od[r] == bd && oi[r] < bi)) { bd = od[r]; bi = oi[r]; }
#pragma unroll
      for (int off = 32; off > 0; off >>= 1) {
        float o2 = __shfl_down(bd, off);
        int i2 = __shfl_down(bi, off);
        if (o2 < bd || (o2 == bd && i2 < bi)) { bd = o2; bi = i2; }
      }
      bi = __shfl(bi, 0);
      if (round == lane) jg = bi;       // register capture: lane r owns round-r winner
#pragma unroll
      for (int r = 0; r < 8; ++r) if (oi[r] == bi) od[r] = F32_INF;
    }
  }
  __syncthreads();   // ld/li dead everywhere before any hbuf write

  // ---- Phase 2: MFMA bf16 MLP (unchanged math) ----
  const float* pp = point + (bbase + jg) * 3;
  const float dx = pp[0] - cx, dy = pp[1] - cy, dz = pp[2] - cz;

  bf16x8 a1[4][2];
  bf16x8 a2[4];
#pragma unroll
  for (int mt = 0; mt < 4; ++mt) {
    int srcl = mt * 16 + col16;
    int jmt = __shfl(jg, srcl);
    const ushort_t* rp = xyzbf + (bbase + (size_t)jmt) * CIN + quad * 8;
    a1[mt][0] = *(const bf16x8*)(rp);
    a1[mt][1] = *(const bf16x8*)(rp + 32);
    float ddx = __shfl(dx, srcl), ddy = __shfl(dy, srcl), ddz = __shfl(dz, srcl);
    bf16x8 t2 = {0, 0, 0, 0, 0, 0, 0, 0};
    if (quad == 0) {
      t2[0] = (short)f2bf(ddx); t2[1] = (short)f2bf(ddy); t2[2] = (short)f2bf(ddz);
    }
    a2[mt] = t2;
  }

  bf16x8 bw1[4][3];
#pragma unroll
  for (int nt = 0; nt < 4; ++nt)
#pragma unroll
    for (int ks = 0; ks < 3; ++ks)
      bw1[nt][ks] = *(const bf16x8*)(w1f + ((size_t)(nt * 3 + ks) * 64 + lane) * 8);
  f32x4 acc1[4][4];
#pragma unroll
  for (int nt = 0; nt < 4; ++nt) {
    float bv = b1[nt * 16 + col16];
#pragma unroll
    for (int mt = 0; mt < 4; ++mt) { f32x4 v = {bv, bv, bv, bv}; acc1[mt][nt] = v; }
  }
#pragma unroll
  for (int mt = 0; mt < 4; ++mt)
#pragma unroll
    for (int nt = 0; nt < 4; ++nt) {
      acc1[mt][nt] = __builtin_amdgcn_mfma_f32_16x16x32_bf16(a1[mt][0], bw1[nt][0], acc1[mt][nt], 0, 0, 0);
      acc1[mt][nt] = __builtin_amdgcn_mfma_f32_16x16x32_bf16(a1[mt][1], bw1[nt][1], acc1[mt][nt], 0, 0, 0);
      acc1[mt][nt] = __builtin_amdgcn_mfma_f32_16x16x32_bf16(a2[mt],    bw1[nt][2], acc1[mt][nt], 0, 0, 0);
    }
#pragma unroll
  for (int mt = 0; mt < 4; ++mt)
#pragma unroll
    for (int nt = 0; nt < 4; ++nt)
#pragma unroll
      for (int reg = 0; reg < 4; ++reg) {
        int row = quad * 4 + reg + mt * 16;
        hb[row * HSTRIDE + col16 + nt * 16] = f2bf(fmaxf(acc1[mt][nt][reg], 0.f));
      }

  bf16x8 a21[4][2];
#pragma unroll
  for (int mt = 0; mt < 4; ++mt)
#pragma unroll
    for (int ks = 0; ks < 2; ++ks)
      a21[mt][ks] = *(const bf16x8*)(hb + (col16 + mt * 16) * HSTRIDE + ks * 32 + quad * 8);
  bf16x8 bw2[4][2];
#pragma unroll
  for (int nt = 0; nt < 4; ++nt)
#pragma unroll
    for (int ks = 0; ks < 2; ++ks)
      bw2[nt][ks] = *(const bf16x8*)(w2f + ((size_t)(nt * 2 + ks) * 64 + lane) * 8);
  f32x4 acc2[4][4];
#pragma unroll
  for (int nt = 0; nt < 4; ++nt) {
    float bv = b2[nt * 16 + col16];
#pragma unroll
    for (int mt = 0; mt < 4; ++mt) { f32x4 v = {bv, bv, bv, bv}; acc2[mt][nt] = v; }
  }
#pragma unroll
  for (int mt = 0; mt < 4; ++mt)
#pragma unroll
    for (int nt = 0; nt < 4; ++nt) {
      acc2[mt][nt] = __builtin_amdgcn_mfma_f32_16x16x32_bf16(a21[mt][0], bw2[nt][0], acc2[mt][nt], 0, 0, 0);
      acc2[mt][nt] = __builtin_amdgcn_mfma_f32_16x16x32_bf16(a21[mt][1], bw2[nt][1], acc2[mt][nt], 0, 0, 0);
    }
#pragma unroll
  for (int mt = 0; mt < 4; ++mt)
#pragma unroll
    for (int nt = 0; nt < 4; ++nt)
#pragma unroll
      for (int reg = 0; reg < 4; ++reg) {
        int row = quad * 4 + reg + mt * 16;
        hb[row * HSTRIDE + col16 + nt * 16] = f2bf(fmaxf(acc2[mt][nt][reg], 0.f));
      }

  bf16x8 a3[4][2];
#pragma unroll
  for (int mt = 0; mt < 4; ++mt)
#pragma unroll
    for (int ks = 0; ks < 2; ++ks)
      a3[mt][ks] = *(const bf16x8*)(hb + (col16 + mt * 16) * HSTRIDE + ks * 32 + quad * 8);
#pragma unroll
  for (int pass = 0; pass < 2; ++pass) {
    bf16x8 bw3[4][2];
#pragma unroll
    for (int nt = 0; nt < 4; ++nt)
#pragma unroll
      for (int ks = 0; ks < 2; ++ks)
        bw3[nt][ks] = *(const bf16x8*)(w3f + ((size_t)((pass * 4 + nt) * 2 + ks) * 64 + lane) * 8);
    f32x4 acc3[4][4];
#pragma unroll
    for (int nt = 0; nt < 4; ++nt) {
      float bv = b3[pass * 64 + nt * 16 + col16];
#pragma unroll
      for (int mt = 0; mt < 4; ++mt) { f32x4 v = {bv, bv, bv, bv}; acc3[mt][nt] = v; }
    }
#pragma unroll
    for (int mt = 0; mt < 4; ++mt)
#pragma unroll
      for (int nt = 0; nt < 4; ++nt) {
        acc3[mt][nt] = __builtin_amdgcn_mfma_f32_16x16x32_bf16(a3[mt][0], bw3[nt][0], acc3[mt][nt], 0, 0, 0);
        acc3[mt][nt] = __builtin_amdgcn_mfma_f32_16x16x32_bf16(a3[mt][1], bw3[nt][1], acc3[mt][nt], 0, 0, 0);
      }
#pragma unroll
    for (int nt = 0; nt < 4; ++nt) {
      float m = -1.0e30f;
#pragma unroll
      for (int mt = 0; mt < 4; ++mt)
#pragma unroll
        for (int reg = 0; reg < 4; ++reg) {
          int row = quad * 4 + reg + mt * 16;
          float v = fmaxf(acc3[mt][nt][reg], 0.f);
          m = fmaxf(m, (row < nv) ? v : -1.0e30f);
        }
      m = fmaxf(m, __shfl_xor(m, 16));
      m = fmaxf(m, __shfl_xor(m, 32));
      if (quad == 0)
        out[(size_t)c * OUTD + pass * 64 + nt * 16 + col16] = m;
    }
  }
}

extern "C" void kernel_launch(void* const* d_in, const int* in_sizes, int n_in,
                              void* d_out, int out_size, void* d_ws, size_t ws_size,
                              hipStream_t stream) {
  const float* xyz   = (const float*)d_in[0];
  const float* point = (const float*)d_in[1];
  // d_in[2] = batch (values == cloud index by construction), d_in[3] = num_samples (64)
  const float* W1 = (const float*)d_in[4];
  const float* b1 = (const float*)d_in[5];
  const float* W2 = (const float*)d_in[6];
  const float* b2 = (const float*)d_in[7];
  const float* W3 = (const float*)d_in[8];
  const float* b3 = (const float*)d_in[9];

  float* out       = (float*)d_out;                     // [16384,128]
  float* cent_out  = out + (size_t)NB * MC * OUTD;      // [16384,3]
  float* batch_out = cent_out + (size_t)NB * MC * 3;    // [16384] (f32 values)

  char* ws = (char*)d_ws;
  float* ctr       = (float*)(ws);                          // 196608 B
  ushort_t* xyzbf  = (ushort_t*)(ws + 4456448);             // 8 MB
  ushort_t* w1f    = (ushort_t*)(ws + 4456448 + 8388608);   // 12288 B
  ushort_t* w2f    = (ushort_t*)(ws + 12845056 + 12288);    // 8192 B
  ushort_t* w3f    = (ushort_t*)(ws + 12857344 + 8192);     // 16384 B

  // blocks 0..15: FPS (1 cloud each); blocks 16..4111: xyz->bf16; block 4112: weights
  fps_prep_kernel<<<NB + 4096 + 1, 256, 0, stream>>>(
      point, xyz, W1, W2, W3, ctr, cent_out, batch_out, xyzbf, w1f, w2f, w3f);
  neigh_mlp_kernel<<<NB * MC / 4, 256, 0, stream>>>(xyzbf, point, ctr,
                                                    w1f, w2f, w3f, b1, b2, b3, out);
}

// Round 8
// 851.813 us; speedup vs baseline: 1.5518x; 1.5518x over previous
//
#include <hip/hip_runtime.h>
#include <cstdint>

#define NB 16      // clouds
#define NP 4096    // points per cloud
#define MC 1024    // FPS centers per cloud
#define KNN 64     // neighbors
#define CIN 64     // input feature dim
#define HID 64
#define OUTD 128

typedef __attribute__((ext_vector_type(8))) short bf16x8;
typedef __attribute__((ext_vector_type(4))) float f32x4;
typedef __attribute__((ext_vector_type(2))) float f32x2;
typedef unsigned long long ull;
typedef unsigned short ushort_t;

#define F32_INF __int_as_float(0x7f800000)

// Bit-exact (vs numpy f32) squared distance: no FMA contraction, numpy sum order.
__device__ __forceinline__ float dist2e(float ax, float ay, float az,
                                        float bx, float by, float bz) {
  float dx = __fsub_rn(ax, bx);
  float dy = __fsub_rn(ay, by);
  float dz = __fsub_rn(az, bz);
  return __fadd_rn(__fadd_rn(__fmul_rn(dx, dx), __fmul_rn(dy, dy)), __fmul_rn(dz, dz));
}

// f32 -> bf16 with round-to-nearest-even.
__device__ __forceinline__ ushort_t f2bf(float f) {
  unsigned u = __float_as_uint(f);
  unsigned r = (u + 0x7FFFu + ((u >> 16) & 1u)) >> 16;
  return (ushort_t)r;
}

// ---- DPP helpers: 64-bit key max-reduce on the VALU pipe ----
template <int CTRL>
__device__ __forceinline__ ull kshift(ull k) {
  int lo = (int)(unsigned)(k & 0xffffffffULL);
  int hi = (int)(unsigned)(k >> 32);
  lo = __builtin_amdgcn_update_dpp(lo, lo, CTRL, 0xf, 0xf, false);
  hi = __builtin_amdgcn_update_dpp(hi, hi, CTRL, 0xf, 0xf, false);
  return ((ull)(unsigned)hi << 32) | (ull)(unsigned)lo;
}
template <int CTRL>
__device__ __forceinline__ ull kred(ull k) {
  ull o = kshift<CTRL>(k);
  return (o > k) ? o : k;
}

// ---------- Prep helper: W -> MFMA B-fragment layout ----------
__device__ __forceinline__ void wfrag_entry(const float* __restrict__ W,
                                            ushort_t* __restrict__ out,
                                            int e, int KS, int K, int N) {
  int lane = e & 63, t2 = e >> 6;
  int ks = t2 % KS, nt = t2 / KS;
  int n = nt * 16 + (lane & 15);
  int kb = ks * 32 + ((lane >> 4) & 3) * 8;
#pragma unroll
  for (int j = 0; j < 8; ++j) {
    int k = kb + j;
    float v = (k < K) ? W[(size_t)k * N + n] : 0.f;
    out[(size_t)e * 8 + j] = f2bf(v);
  }
}

// ============ Kernel 1 (fused): FPS (blocks 0..15, round-3 proven core) + prep ============
// key = (f32bits(d) << 32) | ~idx : u64 max == (max d, tie -> lowest idx).
// Round-3 structure: fused min-update + (bd,br) track -> u64 DPP wave reduce ->
// lane63 kbuf write -> barrier -> uniform kbuf read + 3 selects -> pts[w] read.
// (Rounds 4-6: every restructuring loses — spin-rings storm the DS pipe, ballot adds
// VALU<->SALU wait-states, inline coord tracking bloats the loop. Do not touch.)
// New in r8: dist loop processes point PAIRS as f32x2 so the backend can emit
// v_pk_{add,mul}_f32 (2 FLOP/lane/instr). Per-element op sequence and tie-breaks are
// bit-identical; fp contract(off) replaces the __f*_rn guard against fma fusion.
__global__ __launch_bounds__(256) void fps_prep_kernel(
    const float* __restrict__ point, const float* __restrict__ xyz,
    const float* __restrict__ W1, const float* __restrict__ W2, const float* __restrict__ W3,
    float* __restrict__ ctr, float* __restrict__ cent_out, float* __restrict__ batch_out,
    ushort_t* __restrict__ xyzbf, ushort_t* __restrict__ w1f,
    ushort_t* __restrict__ w2f, ushort_t* __restrict__ w3f) {
#pragma clang fp contract(off)
  const int blk = blockIdx.x;
  const int t = threadIdx.x;
  if (blk >= NB) {  // ---- prep path (independent; runs on idle CUs under fps) ----
    const int pb = blk - NB;
    if (pb < 4096) {
      size_t i = ((size_t)pb * 256 + t) * 4;
      float4 v = *(const float4*)(xyz + i);
      unsigned lo = (unsigned)f2bf(v.x) | ((unsigned)f2bf(v.y) << 16);
      unsigned hi = (unsigned)f2bf(v.z) | ((unsigned)f2bf(v.w) << 16);
      uint2 o; o.x = lo; o.y = hi;
      *(uint2*)(xyzbf + i) = o;
    } else {
      for (int e = t; e < 4 * 3 * 64; e += 256) wfrag_entry(W1, w1f, e, 3, CIN + 3, HID);
      for (int e = t; e < 4 * 2 * 64; e += 256) wfrag_entry(W2, w2f, e, 2, HID, HID);
      for (int e = t; e < 8 * 2 * 64; e += 256) wfrag_entry(W3, w3f, e, 2, HID, OUTD);
    }
    return;
  }
  // ---- FPS path ----
  const int b = blk;
  const int lane = t & 63, wid = t >> 6;
  __shared__ float4 pts[NP];       // 64 KB
  __shared__ ull kbuf[2][4];
  __shared__ int whist[MC];        // 4 KB
  const float* p = point + (size_t)b * NP * 3;
  for (int i = t; i < NP; i += 256) {
    float4 v; v.x = p[3 * i]; v.y = p[3 * i + 1]; v.z = p[3 * i + 2]; v.w = 0.f;
    pts[i] = v;
  }
  if (t == 0) whist[0] = 0;  // sample 0 is index 0
  __syncthreads();
  f32x2 qx2[8], qy2[8], qz2[8], d2v[8];
#pragma unroll
  for (int k = 0; k < 8; ++k) {
    float4 v0 = pts[t * 16 + 2 * k];
    float4 v1 = pts[t * 16 + 2 * k + 1];
    qx2[k].x = v0.x; qx2[k].y = v1.x;
    qy2[k].x = v0.y; qy2[k].y = v1.y;
    qz2[k].x = v0.z; qz2[k].y = v1.z;
    d2v[k].x = F32_INF; d2v[k].y = F32_INF;   // min(inf, d0) == d0 exactly
  }
  int w = 0;
  for (int it = 1; it < MC; ++it) {
    float4 wp = pts[w];
    f32x2 wxx; wxx.x = wp.x; wxx.y = wp.x;
    f32x2 wyy; wyy.x = wp.y; wyy.y = wp.y;
    f32x2 wzz; wzz.x = wp.z; wzz.y = wp.z;
    float bd = -1.0f; int br = 0;
#pragma unroll
    for (int k = 0; k < 8; ++k) {   // packed dist + min-update + first-max argmax
      f32x2 dx = qx2[k] - wxx;
      f32x2 dy = qy2[k] - wyy;
      f32x2 dz = qz2[k] - wzz;
      f32x2 nd = (dx * dx + dy * dy) + dz * dz;  // per-element numpy order, no fma
      f32x2 dv;
      dv.x = fminf(d2v[k].x, nd.x);
      dv.y = fminf(d2v[k].y, nd.y);
      d2v[k] = dv;
      bool p1 = dv.y > dv.x;                     // strict: tie keeps lower r
      float pd = p1 ? dv.y : dv.x;
      int pr = 2 * k + (p1 ? 1 : 0);
      if (pd > bd) { bd = pd; br = pr; }         // strict: first-occurrence wins
    }
    unsigned gi = (unsigned)(t * 16 + br);
    ull key = ((ull)__float_as_uint(bd) << 32) | (ull)(unsigned)~gi;
    key = kred<0x111>(key);  // row_shr:1
    key = kred<0x112>(key);  // row_shr:2
    key = kred<0x114>(key);  // row_shr:4
    key = kred<0x118>(key);  // row_shr:8   -> lane 15/31/47/63 = row max
    key = kred<0x142>(key);  // row_bcast:15
    key = kred<0x143>(key);  // row_bcast:31 -> lane 63 = wave max
    const int par = it & 1;                // parity: slot reused only after 2 barriers
    if (lane == 63) kbuf[par][wid] = key;
    __syncthreads();
    ull k0 = kbuf[par][0], k1 = kbuf[par][1], k2 = kbuf[par][2], k3 = kbuf[par][3];
    ull ka = (k0 > k1) ? k0 : k1;          // uniform LDS broadcast reads; every lane
    ull kb = (k2 > k3) ? k2 : k3;          // computes w -> no readlane on the path
    ull km = (ka > kb) ? ka : kb;
    w = (int)~(unsigned)(km & 0xffffffffULL);
    if (t == 0) whist[it] = w;             // ds_write: cheap lgkm drain at the barrier
  }
  __syncthreads();
  for (int s = t; s < MC; s += 256) {      // one-shot output writeback
    int wi = whist[s];
    float4 wp = pts[wi];
    size_t o = (size_t)b * MC + s;
    ctr[3*o] = wp.x; ctr[3*o+1] = wp.y; ctr[3*o+2] = wp.z;
    cent_out[3*o] = wp.x; cent_out[3*o+1] = wp.y; cent_out[3*o+2] = wp.z;
    batch_out[o] = (float)b;  // batch = arange // NP == cloud index
  }
}

// ------------- Kernel 2: radius + K-nearest SET selection, one wave per center -------------
// Standalone (low VGPR, 64-thr blocks -> high occupancy for this latency-bound scan;
// r7 showed fusing it into the MFMA kernel collapses its TLP).
// Selection: output is a SET (masked max-agg is order-invariant), so instead of 64
// serial wave-argmin rounds, binary-search tau = 64th-smallest d2 on f32 bit patterns
// (~30 uniform ballot-count steps), then emit {d2 < tau} + lowest-index ties at tau.
// Compaction preserves point-index order => tie rank = slot order = lax.top_k stability.
__global__ void neigh_kernel(const float* __restrict__ point,
                             const float* __restrict__ ctr,
                             int* __restrict__ nidx, int* __restrict__ ncnt) {
  const int c = blockIdx.x;
  const int b = c >> 10;  // c / MC
  const int lane = threadIdx.x;  // 64 threads = 1 wave
  __shared__ float ld[512];
  __shared__ int li[512];
  const float R2 = (float)(0.2 * 0.2);
  const float cx = ctr[3*c], cy = ctr[3*c+1], cz = ctr[3*c+2];
  const float* p = point + (size_t)b * NP * 3;
  int cnt = 0;
  for (int s = 0; s < NP / 64; ++s) {   // compact in-ball candidates into LDS
    int j = s * 64 + lane;
    float d2 = dist2e(cx, cy, cz, p[3*j], p[3*j+1], p[3*j+2]);
    bool v = d2 < R2;
    ull m = __ballot(v);
    if (v) {
      int pos = cnt + __popcll(m & ((1ull << lane) - 1ull));
      if (pos < 512) { ld[pos] = d2; li[pos] = j; }
    }
    cnt += __popcll(m);
  }
  if (cnt > 512) cnt = 512;
  __syncthreads();
  if (cnt <= KNN) {
    nidx[(size_t)c * KNN + lane] = (lane < cnt) ? li[lane] : 0;
  } else {
    unsigned ob[8]; int oi[8];
#pragma unroll
    for (int r = 0; r < 8; ++r) {
      int s2 = lane + r * 64;
      if (s2 < cnt) { ob[r] = __float_as_uint(ld[s2]); oi[r] = li[s2]; }
      else { ob[r] = 0xFFFFFFFFu; oi[r] = 0; }
    }
    // tau = min{v : count(bits <= v) >= KNN}; all candidate bits < bits(0.04f)
    unsigned L = 0u, H = 0x3D23D70Au;
    while (L < H) {                        // wave-uniform ~30 iterations
      unsigned mid = (L + H) >> 1;
      int cle = 0;
#pragma unroll
      for (int r = 0; r < 8; ++r) cle += (int)__popcll(__ballot(ob[r] <= mid));
      if (cle >= KNN) H = mid; else L = mid + 1;
    }
    const unsigned tau = H;
    int c_lt = 0;
#pragma unroll
    for (int r = 0; r < 8; ++r) c_lt += (int)__popcll(__ballot(ob[r] < tau));
    const int need = KNN - c_lt;           // ties at tau to take, lowest index first
    const ull below = (1ull << lane) - 1ull;
    int outpos = 0, eqc = 0;
#pragma unroll
    for (int r = 0; r < 8; ++r) {          // slot order == index order (sorted compaction)
      ull meq = __ballot(ob[r] == tau);
      int eqrank = eqc + (int)__popcll(meq & below);
      bool sel = (ob[r] < tau) || ((ob[r] == tau) && (eqrank < need));
      ull msel = __ballot(sel);
      if (sel) {
        int posn = outpos + (int)__popcll(msel & below);
        nidx[(size_t)c * KNN + posn] = oi[r];
      }
      outpos += (int)__popcll(msel);
      eqc += (int)__popcll(meq);
    }
  }
  if (lane == 0) ncnt[c] = (cnt < KNN) ? cnt : KNN;
}

// ---------- Kernel 3: MFMA bf16 MLP, one wave per center, 4 centers/block ----------
#define HSTRIDE 72   // bf16 elems per hbuf row: 144 B = 16B-aligned, 2-way-conflict-free b128
__global__ __launch_bounds__(256) void mlp_kernel(
    const ushort_t* __restrict__ xyzbf, const float* __restrict__ point,
    const float* __restrict__ ctr, const int* __restrict__ nidx,
    const int* __restrict__ ncnt,
    const ushort_t* __restrict__ w1f, const ushort_t* __restrict__ w2f,
    const ushort_t* __restrict__ w3f,
    const float* __restrict__ b1, const float* __restrict__ b2,
    const float* __restrict__ b3,
    float* __restrict__ out) {
  const int wv = threadIdx.x >> 6, lane = threadIdx.x & 63;
  const int quad = lane >> 4, col16 = lane & 15;
  const int c = blockIdx.x * 4 + wv;
  const int bcl = c >> 10;
  const size_t bbase = (size_t)bcl * NP;
  __shared__ ushort_t hbuf_all[4 * 64 * HSTRIDE];  // 36864 B, wave-private slices
  ushort_t* hb = hbuf_all + wv * 64 * HSTRIDE;

  const int jg = nidx[(size_t)c * KNN + lane];
  const int nv = ncnt[c];
  const float cx = ctr[3*c], cy = ctr[3*c+1], cz = ctr[3*c+2];
  const float* pp = point + (bbase + jg) * 3;
  const float dx = pp[0] - cx, dy = pp[1] - cy, dz = pp[2] - cz;

  bf16x8 a1[4][2];
  bf16x8 a2[4];
#pragma unroll
  for (int mt = 0; mt < 4; ++mt) {
    int srcl = mt * 16 + col16;
    int jmt = __shfl(jg, srcl);
    const ushort_t* rp = xyzbf + (bbase + (size_t)jmt) * CIN + quad * 8;
    a1[mt][0] = *(const bf16x8*)(rp);
    a1[mt][1] = *(const bf16x8*)(rp + 32);
    float ddx = __shfl(dx, srcl), ddy = __shfl(dy, srcl), ddz = __shfl(dz, srcl);
    bf16x8 t2 = {0, 0, 0, 0, 0, 0, 0, 0};
    if (quad == 0) {
      t2[0] = (short)f2bf(ddx); t2[1] = (short)f2bf(ddy); t2[2] = (short)f2bf(ddz);
    }
    a2[mt] = t2;
  }

  bf16x8 bw1[4][3];
#pragma unroll
  for (int nt = 0; nt < 4; ++nt)
#pragma unroll
    for (int ks = 0; ks < 3; ++ks)
      bw1[nt][ks] = *(const bf16x8*)(w1f + ((size_t)(nt * 3 + ks) * 64 + lane) * 8);
  f32x4 acc1[4][4];
#pragma unroll
  for (int nt = 0; nt < 4; ++nt) {
    float bv = b1[nt * 16 + col16];
#pragma unroll
    for (int mt = 0; mt < 4; ++mt) { f32x4 v = {bv, bv, bv, bv}; acc1[mt][nt] = v; }
  }
#pragma unroll
  for (int mt = 0; mt < 4; ++mt)
#pragma unroll
    for (int nt = 0; nt < 4; ++nt) {
      acc1[mt][nt] = __builtin_amdgcn_mfma_f32_16x16x32_bf16(a1[mt][0], bw1[nt][0], acc1[mt][nt], 0, 0, 0);
      acc1[mt][nt] = __builtin_amdgcn_mfma_f32_16x16x32_bf16(a1[mt][1], bw1[nt][1], acc1[mt][nt], 0, 0, 0);
      acc1[mt][nt] = __builtin_amdgcn_mfma_f32_16x16x32_bf16(a2[mt],    bw1[nt][2], acc1[mt][nt], 0, 0, 0);
    }
#pragma unroll
  for (int mt = 0; mt < 4; ++mt)
#pragma unroll
    for (int nt = 0; nt < 4; ++nt)
#pragma unroll
      for (int reg = 0; reg < 4; ++reg) {
        int row = quad * 4 + reg + mt * 16;
        hb[row * HSTRIDE + col16 + nt * 16] = f2bf(fmaxf(acc1[mt][nt][reg], 0.f));
      }

  bf16x8 a21[4][2];
#pragma unroll
  for (int mt = 0; mt < 4; ++mt)
#pragma unroll
    for (int ks = 0; ks < 2; ++ks)
      a21[mt][ks] = *(const bf16x8*)(hb + (col16 + mt * 16) * HSTRIDE + ks * 32 + quad * 8);
  bf16x8 bw2[4][2];
#pragma unroll
  for (int nt = 0; nt < 4; ++nt)
#pragma unroll
    for (int ks = 0; ks < 2; ++ks)
      bw2[nt][ks] = *(const bf16x8*)(w2f + ((size_t)(nt * 2 + ks) * 64 + lane) * 8);
  f32x4 acc2[4][4];
#pragma unroll
  for (int nt = 0; nt < 4; ++nt) {
    float bv = b2[nt * 16 + col16];
#pragma unroll
    for (int mt = 0; mt < 4; ++mt) { f32x4 v = {bv, bv, bv, bv}; acc2[mt][nt] = v; }
  }
#pragma unroll
  for (int mt = 0; mt < 4; ++mt)
#pragma unroll
    for (int nt = 0; nt < 4; ++nt) {
      acc2[mt][nt] = __builtin_amdgcn_mfma_f32_16x16x32_bf16(a21[mt][0], bw2[nt][0], acc2[mt][nt], 0, 0, 0);
      acc2[mt][nt] = __builtin_amdgcn_mfma_f32_16x16x32_bf16(a21[mt][1], bw2[nt][1], acc2[mt][nt], 0, 0, 0);
    }
#pragma unroll
  for (int mt = 0; mt < 4; ++mt)
#pragma unroll
    for (int nt = 0; nt < 4; ++nt)
#pragma unroll
      for (int reg = 0; reg < 4; ++reg) {
        int row = quad * 4 + reg + mt * 16;
        hb[row * HSTRIDE + col16 + nt * 16] = f2bf(fmaxf(acc2[mt][nt][reg], 0.f));
      }

  bf16x8 a3[4][2];
#pragma unroll
  for (int mt = 0; mt < 4; ++mt)
#pragma unroll
    for (int ks = 0; ks < 2; ++ks)
      a3[mt][ks] = *(const bf16x8*)(hb + (col16 + mt * 16) * HSTRIDE + ks * 32 + quad * 8);
#pragma unroll
  for (int pass = 0; pass < 2; ++pass) {
    bf16x8 bw3[4][2];
#pragma unroll
    for (int nt = 0; nt < 4; ++nt)
#pragma unroll
      for (int ks = 0; ks < 2; ++ks)
        bw3[nt][ks] = *(const bf16x8*)(w3f + ((size_t)((pass * 4 + nt) * 2 + ks) * 64 + lane) * 8);
    f32x4 acc3[4][4];
#pragma unroll
    for (int nt = 0; nt < 4; ++nt) {
      float bv = b3[pass * 64 + nt * 16 + col16];
#pragma unroll
      for (int mt = 0; mt < 4; ++mt) { f32x4 v = {bv, bv, bv, bv}; acc3[mt][nt] = v; }
    }
#pragma unroll
    for (int mt = 0; mt < 4; ++mt)
#pragma unroll
      for (int nt = 0; nt < 4; ++nt) {
        acc3[mt][nt] = __builtin_amdgcn_mfma_f32_16x16x32_bf16(a3[mt][0], bw3[nt][0], acc3[mt][nt], 0, 0, 0);
        acc3[mt][nt] = __builtin_amdgcn_mfma_f32_16x16x32_bf16(a3[mt][1], bw3[nt][1], acc3[mt][nt], 0, 0, 0);
      }
#pragma unroll
    for (int nt = 0; nt < 4; ++nt) {
      float m = -1.0e30f;
#pragma unroll
      for (int mt = 0; mt < 4; ++mt)
#pragma unroll
        for (int reg = 0; reg < 4; ++reg) {
          int row = quad * 4 + reg + mt * 16;
          float v = fmaxf(acc3[mt][nt][reg], 0.f);
          m = fmaxf(m, (row < nv) ? v : -1.0e30f);
        }
      m = fmaxf(m, __shfl_xor(m, 16));
      m = fmaxf(m, __shfl_xor(m, 32));
      if (quad == 0)
        out[(size_t)c * OUTD + pass * 64 + nt * 16 + col16] = m;
    }
  }
}

extern "C" void kernel_launch(void* const* d_in, const int* in_sizes, int n_in,
                              void* d_out, int out_size, void* d_ws, size_t ws_size,
                              hipStream_t stream) {
  const float* xyz   = (const float*)d_in[0];
  const float* point = (const float*)d_in[1];
  // d_in[2] = batch (values == cloud index by construction), d_in[3] = num_samples (64)
  const float* W1 = (const float*)d_in[4];
  const float* b1 = (const float*)d_in[5];
  const float* W2 = (const float*)d_in[6];
  const float* b2 = (const float*)d_in[7];
  const float* W3 = (const float*)d_in[8];
  const float* b3 = (const float*)d_in[9];

  float* out       = (float*)d_out;                     // [16384,128]
  float* cent_out  = out + (size_t)NB * MC * OUTD;      // [16384,3]
  float* batch_out = cent_out + (size_t)NB * MC * 3;    // [16384] (f32 values)

  char* ws = (char*)d_ws;
  float* ctr       = (float*)(ws);                          // 196608 B
  int*   nidx      = (int*)(ws + 196608);                   // 4 MB
  int*   ncnt      = (int*)(ws + 196608 + 4194304);         // 64 KB
  ushort_t* xyzbf  = (ushort_t*)(ws + 4456448);             // 8 MB
  ushort_t* w1f    = (ushort_t*)(ws + 4456448 + 8388608);   // 12288 B
  ushort_t* w2f    = (ushort_t*)(ws + 12845056 + 12288);    // 8192 B
  ushort_t* w3f    = (ushort_t*)(ws + 12857344 + 8192);     // 16384 B

  // blocks 0..15: FPS (1 cloud each); blocks 16..4111: xyz->bf16; block 4112: weights
  fps_prep_kernel<<<NB + 4096 + 1, 256, 0, stream>>>(
      point, xyz, W1, W2, W3, ctr, cent_out, batch_out, xyzbf, w1f, w2f, w3f);
  neigh_kernel<<<NB * MC, 64, 0, stream>>>(point, ctr, nidx, ncnt);
  mlp_kernel<<<NB * MC / 4, 256, 0, stream>>>(xyzbf, point, ctr, nidx, ncnt,
                                              w1f, w2f, w3f, b1, b2, b3, out);
}